// Round 1
// baseline (1580.493 us; speedup 1.0000x reference)
//
#include <hip/hip_runtime.h>
#include <hip/hip_bf16.h>

// Sinkhorn object matching, scaling-vector formulation.
//   S = Q R^T  (4096x4096, D=256, fp32)
//   K0 = exp(S_aug / 0.1), S_aug has dustbin row/col = z
//   iterate 100x: u = 1/(K0 v); v = 1/(K0^T u)   (v0 = ones)
//   K = diag(u) K0 diag(v); P = K[:M,:N]
// K0 fp32 lives in the K-region of d_out (written by GEMM, scaled in place by
// finalize). bf16 copies of K0 and K0^T (padded stride for 16B-aligned loads)
// live in d_ws and feed the 200 matvecs.

#define MROWS 4096
#define NCOLS 4096
#define DDIM 256
#define MP1 4097          // (M+1) == (N+1)
#define LDPAD 4104        // bf16 row stride, multiple of 8 -> 16B-aligned rows
#define UPAD 4104         // u vector padding so v stays 16B-aligned
#define INV_EPS 10.0f     // 1/SINKHORN_EPSILON

static __device__ __forceinline__ float bf2f(unsigned int u) {
  union { unsigned int i; float f; } c;
  c.i = u << 16;
  return c.f;
}
static __device__ __forceinline__ unsigned short f2bf(float f) {
  __hip_bfloat16 h = __float2bfloat16(f);
  union { __hip_bfloat16 h; unsigned short s; } c;
  c.h = h;
  return c.s;
}

// ---------------------------------------------------------------------------
// S = Q R^T tile GEMM (fp32, 64x64 tile, 256 thr, 4x4 per thread), fused
// epilogue: K0 = exp(10*S) -> fp32 K-region of d_out, bf16 A, bf16 T (=A^T).
// ---------------------------------------------------------------------------
__global__ __launch_bounds__(256) void gemm_exp_kernel(
    const float* __restrict__ Q, const float* __restrict__ R,
    float* __restrict__ Kf, unsigned short* __restrict__ A,
    unsigned short* __restrict__ T)
{
  __shared__ float Qs[64][17];
  __shared__ float Rs[64][17];
  const int tid = threadIdx.x;
  const int tx = tid & 15;        // output col group
  const int ty = tid >> 4;        // output row group
  const int rb = blockIdx.y * 64;
  const int cb = blockIdx.x * 64;
  const int lr = tid >> 2;        // load row 0..63
  const int lc = (tid & 3) * 4;   // load col 0,4,8,12

  float acc[4][4] = {};
  for (int k0 = 0; k0 < DDIM; k0 += 16) {
    float4 q = *reinterpret_cast<const float4*>(&Q[(size_t)(rb + lr) * DDIM + k0 + lc]);
    float4 r = *reinterpret_cast<const float4*>(&R[(size_t)(cb + lr) * DDIM + k0 + lc]);
    __syncthreads();
    Qs[lr][lc + 0] = q.x; Qs[lr][lc + 1] = q.y; Qs[lr][lc + 2] = q.z; Qs[lr][lc + 3] = q.w;
    Rs[lr][lc + 0] = r.x; Rs[lr][lc + 1] = r.y; Rs[lr][lc + 2] = r.z; Rs[lr][lc + 3] = r.w;
    __syncthreads();
#pragma unroll
    for (int kk = 0; kk < 16; ++kk) {
      const float a0 = Qs[ty * 4 + 0][kk];
      const float a1 = Qs[ty * 4 + 1][kk];
      const float a2 = Qs[ty * 4 + 2][kk];
      const float a3 = Qs[ty * 4 + 3][kk];
      const float b0 = Rs[tx * 4 + 0][kk];
      const float b1 = Rs[tx * 4 + 1][kk];
      const float b2 = Rs[tx * 4 + 2][kk];
      const float b3 = Rs[tx * 4 + 3][kk];
      acc[0][0] += a0 * b0; acc[0][1] += a0 * b1; acc[0][2] += a0 * b2; acc[0][3] += a0 * b3;
      acc[1][0] += a1 * b0; acc[1][1] += a1 * b1; acc[1][2] += a1 * b2; acc[1][3] += a1 * b3;
      acc[2][0] += a2 * b0; acc[2][1] += a2 * b1; acc[2][2] += a2 * b2; acc[2][3] += a2 * b3;
      acc[3][0] += a3 * b0; acc[3][1] += a3 * b1; acc[3][2] += a3 * b2; acc[3][3] += a3 * b3;
    }
  }
#pragma unroll
  for (int i = 0; i < 4; ++i) {
#pragma unroll
    for (int j = 0; j < 4; ++j) {
      const int row = rb + ty * 4 + i;
      const int col = cb + tx * 4 + j;
      const float kv = __expf(acc[i][j] * INV_EPS);
      Kf[(size_t)row * MP1 + col] = kv;
      const unsigned short b = f2bf(kv);
      A[(size_t)row * LDPAD + col] = b;
      T[(size_t)col * LDPAD + row] = b;
    }
  }
}

// ---------------------------------------------------------------------------
// Fill dustbin row/col (value exp(z/eps)) in Kf, A, T; init v = ones.
// ---------------------------------------------------------------------------
__global__ void edges_kernel(const float* __restrict__ zp, float* __restrict__ Kf,
                             unsigned short* __restrict__ A, unsigned short* __restrict__ T,
                             float* __restrict__ v)
{
  const int i = blockIdx.x * 256 + threadIdx.x;
  if (i >= MP1) return;
  const float E = __expf(zp[0] * INV_EPS);
  const unsigned short eb = f2bf(E);
  Kf[(size_t)MROWS * MP1 + i] = E;    // last row
  Kf[(size_t)i * MP1 + NCOLS] = E;    // last col (covers corner)
  A[(size_t)MROWS * LDPAD + i] = eb;
  A[(size_t)i * LDPAD + NCOLS] = eb;
  T[(size_t)NCOLS * LDPAD + i] = eb;
  T[(size_t)i * LDPAD + MROWS] = eb;
  v[i] = 1.0f;
}

// ---------------------------------------------------------------------------
// out[row] = 1 / sum_j Kb[row][j] * x[j]     (rows = cols = 4097)
// one wave per row; 16B bf16 loads (rows 16B-aligned via LDPAD).
// ---------------------------------------------------------------------------
__global__ __launch_bounds__(256) void rowdot_kernel(
    const unsigned short* __restrict__ Kb, const float* __restrict__ x,
    float* __restrict__ out, int rows)
{
  const int lane = threadIdx.x & 63;
  const int wid = threadIdx.x >> 6;
  const int row = blockIdx.x * 4 + wid;
  if (row >= rows) return;
  const unsigned short* rp = Kb + (size_t)row * LDPAD;
  float acc = 0.f;
#pragma unroll
  for (int it = 0; it < 8; ++it) {
    const int j = (it * 64 + lane) * 8;   // 8 bf16 per lane per iter
    const uint4 kv = *reinterpret_cast<const uint4*>(rp + j);
    const float4 x0 = *reinterpret_cast<const float4*>(x + j);
    const float4 x1 = *reinterpret_cast<const float4*>(x + j + 4);
    acc += bf2f(kv.x & 0xffffu) * x0.x;
    acc += bf2f(kv.x >> 16)     * x0.y;
    acc += bf2f(kv.y & 0xffffu) * x0.z;
    acc += bf2f(kv.y >> 16)     * x0.w;
    acc += bf2f(kv.z & 0xffffu) * x1.x;
    acc += bf2f(kv.z >> 16)     * x1.y;
    acc += bf2f(kv.w & 0xffffu) * x1.z;
    acc += bf2f(kv.w >> 16)     * x1.w;
  }
  if (lane == 0) acc += bf2f((unsigned int)rp[4096]) * x[4096];  // tail col 4096
#pragma unroll
  for (int off = 32; off > 0; off >>= 1) acc += __shfl_down(acc, off, 64);
  if (lane == 0) out[row] = 1.0f / acc;
}

// ---------------------------------------------------------------------------
// K[row][col] = u[row] * (K0[row][col] * v[col]) in place (fp32 d_out region);
// P[row][col] = same for interior. Grid-stride over float4 groups.
// ---------------------------------------------------------------------------
__global__ __launch_bounds__(256) void finalize_kernel(
    float* __restrict__ Kf, float* __restrict__ P,
    const float* __restrict__ u, const float* __restrict__ v)
{
  const size_t n4 = ((size_t)MP1 * MP1) / 4;   // 4196352 full groups, 1 tail elem
  const size_t stride = (size_t)gridDim.x * blockDim.x;
  for (size_t f4 = (size_t)blockIdx.x * blockDim.x + threadIdx.x; f4 < n4; f4 += stride) {
    float4 kv = *reinterpret_cast<float4*>(Kf + f4 * 4);
    float e[4] = {kv.x, kv.y, kv.z, kv.w};
#pragma unroll
    for (int k = 0; k < 4; ++k) {
      const unsigned int flat = (unsigned int)(f4 * 4 + k);
      const unsigned int row = flat / (unsigned int)MP1;
      const unsigned int col = flat - row * (unsigned int)MP1;
      const float val = u[row] * (e[k] * v[col]);
      e[k] = val;
      if (row < MROWS && col < NCOLS) P[(size_t)row * NCOLS + col] = val;
    }
    kv.x = e[0]; kv.y = e[1]; kv.z = e[2]; kv.w = e[3];
    *reinterpret_cast<float4*>(Kf + f4 * 4) = kv;
  }
  if (blockIdx.x == 0 && threadIdx.x == 0) {   // tail element (corner)
    const size_t flat = (size_t)MP1 * MP1 - 1;
    Kf[flat] = u[MP1 - 1] * (Kf[flat] * v[MP1 - 1]);
  }
}

extern "C" void kernel_launch(void* const* d_in, const int* in_sizes, int n_in,
                              void* d_out, int out_size, void* d_ws, size_t ws_size,
                              hipStream_t stream) {
  const float* Q = (const float*)d_in[0];
  const float* R = (const float*)d_in[1];
  const float* z = (const float*)d_in[2];

  float* P = (float*)d_out;
  float* Kf = P + (size_t)MROWS * NCOLS;   // K-region of d_out holds fp32 K0, then K

  const size_t matElems = (size_t)MP1 * LDPAD;   // bf16 elements per matrix
  unsigned short* A = (unsigned short*)d_ws;     // K0 bf16
  unsigned short* T = A + matElems;              // K0^T bf16
  float* u = (float*)(T + matElems);             // 16B-aligned (4*matElems % 16 == 0)
  float* v = u + UPAD;                           // 16B-aligned (UPAD*4 % 16 == 0)

  gemm_exp_kernel<<<dim3(64, 64), 256, 0, stream>>>(Q, R, Kf, A, T);
  edges_kernel<<<(MP1 + 255) / 256, 256, 0, stream>>>(z, Kf, A, T, v);
  for (int it = 0; it < 100; ++it) {
    rowdot_kernel<<<(MP1 + 3) / 4, 256, 0, stream>>>(A, v, u, MP1);
    rowdot_kernel<<<(MP1 + 3) / 4, 256, 0, stream>>>(T, u, v, MP1);
  }
  finalize_kernel<<<2048, 256, 0, stream>>>(Kf, P, u, v);
}

// Round 2
// 1442.294 us; speedup vs baseline: 1.0958x; 1.0958x over previous
//
#include <hip/hip_runtime.h>
#include <hip/hip_bf16.h>

// Sinkhorn object matching, scaling-vector formulation.
//   S = Q R^T  (4096x4096, D=256), K0 = exp(S_aug/0.1) with dustbin z
//   100x: u = 1/(K0 v); v = 1/(K0^T u); K = diag(u) K0 diag(v); P = K interior
// GEMM1 (MFMA bf16): builds bf16 A = K0 and T = K0^T in d_ws for the matvecs.
// 200 rowdot matvecs iterate u,v.
// GEMM2 (MFMA bf16): recomputes exp(10 S) in fp32, scales by u_i v_j, writes
// P and K directly (no fp32 K0 buffer, no finalize pass).

#define MROWS 4096
#define NCOLS 4096
#define DDIM 256
#define MP1 4097          // (M+1) == (N+1)
#define LDPAD 4104        // bf16 row stride, multiple of 8 -> 16B-aligned rows
#define UPAD 4104
#define INV_EPS 10.0f

typedef __attribute__((ext_vector_type(8))) short bf16x8;
typedef __attribute__((ext_vector_type(4))) float f32x4;
typedef __attribute__((ext_vector_type(4))) unsigned short u16x4;

static __device__ __forceinline__ float bf2f(unsigned int u) {
  union { unsigned int i; float f; } c;
  c.i = u << 16;
  return c.f;
}
static __device__ __forceinline__ unsigned short f2bf(float f) {
  __hip_bfloat16 h = __float2bfloat16(f);
  union { __hip_bfloat16 h; unsigned short s; } c;
  c.h = h;
  return c.s;
}

// ---------------------------------------------------------------------------
// MFMA bf16 GEMM core: 128x128 tile, 4 waves (2x2), each wave 64x64 =
// 4x4 fragments of 16x16x32. K = 256 in 8 steps of 32.
// MODE 0: epilogue kv=exp(10S) -> bf16 A[row][col], bf16 T[col][row] (ushort4
//         packed over the 4 contiguous rows each lane owns).
// MODE 1: epilogue val = u[row]*exp(10S)*v[col] -> fp32 K (stride MP1) and P.
// ---------------------------------------------------------------------------
template <int MODE>
__global__ __launch_bounds__(256) void mfma_gemm_kernel(
    const float* __restrict__ Q, const float* __restrict__ R,
    unsigned short* __restrict__ A, unsigned short* __restrict__ T,
    float* __restrict__ Kf, float* __restrict__ P,
    const float* __restrict__ u, const float* __restrict__ v)
{
  __shared__ unsigned short Qs[128][40];   // stride 40 bf16 (80B): 2-way max
  __shared__ unsigned short Rs[128][40];

  const int tid = threadIdx.x;
  const int lane = tid & 63;
  const int wid = tid >> 6;
  const int wy = wid >> 1;        // wave row (0..1)
  const int wx = wid & 1;         // wave col (0..1)
  const int rb = blockIdx.y * 128;
  const int cb = blockIdx.x * 128;
  const int lr = tid >> 3;        // staging row 0..31 (+32*i)
  const int lf = (tid & 7) * 4;   // staging k offset (floats)

  f32x4 acc[4][4];
#pragma unroll
  for (int m = 0; m < 4; ++m)
#pragma unroll
    for (int n = 0; n < 4; ++n)
      acc[m][n] = (f32x4){0.f, 0.f, 0.f, 0.f};

  for (int k0 = 0; k0 < DDIM; k0 += 32) {
    float4 qv[4], rv[4];
#pragma unroll
    for (int i = 0; i < 4; ++i) {
      qv[i] = *reinterpret_cast<const float4*>(&Q[(size_t)(rb + lr + 32 * i) * DDIM + k0 + lf]);
      rv[i] = *reinterpret_cast<const float4*>(&R[(size_t)(cb + lr + 32 * i) * DDIM + k0 + lf]);
    }
    __syncthreads();
#pragma unroll
    for (int i = 0; i < 4; ++i) {
      u16x4 qs = {f2bf(qv[i].x), f2bf(qv[i].y), f2bf(qv[i].z), f2bf(qv[i].w)};
      u16x4 rs = {f2bf(rv[i].x), f2bf(rv[i].y), f2bf(rv[i].z), f2bf(rv[i].w)};
      *reinterpret_cast<u16x4*>(&Qs[lr + 32 * i][lf]) = qs;
      *reinterpret_cast<u16x4*>(&Rs[lr + 32 * i][lf]) = rs;
    }
    __syncthreads();

    const int ko = (lane >> 4) * 8;   // k sub-offset for this lane group
    const int fr = lane & 15;         // fragment row/col within 16
    bf16x8 af[4], bg[4];
#pragma unroll
    for (int m = 0; m < 4; ++m)
      af[m] = *reinterpret_cast<const bf16x8*>(&Qs[wy * 64 + m * 16 + fr][ko]);
#pragma unroll
    for (int n = 0; n < 4; ++n)
      bg[n] = *reinterpret_cast<const bf16x8*>(&Rs[wx * 64 + n * 16 + fr][ko]);
#pragma unroll
    for (int m = 0; m < 4; ++m)
#pragma unroll
      for (int n = 0; n < 4; ++n)
        acc[m][n] = __builtin_amdgcn_mfma_f32_16x16x32_bf16(af[m], bg[n], acc[m][n], 0, 0, 0);
  }

  // Epilogue. C/D layout (16x16x32): col = lane&15, row = (lane>>4)*4 + reg.
  const int r0 = (lane >> 4) * 4;
  const int fc = lane & 15;
#pragma unroll
  for (int m = 0; m < 4; ++m) {
    const int row0 = rb + wy * 64 + m * 16 + r0;
    float uu[4];
    if (MODE == 1) {
#pragma unroll
      for (int r = 0; r < 4; ++r) uu[r] = u[row0 + r];
    }
#pragma unroll
    for (int n = 0; n < 4; ++n) {
      const int col = cb + wx * 64 + n * 16 + fc;
      if (MODE == 0) {
        u16x4 tp;
#pragma unroll
        for (int r = 0; r < 4; ++r) {
          const float kv = __expf(acc[m][n][r] * INV_EPS);
          const unsigned short b = f2bf(kv);
          A[(size_t)(row0 + r) * LDPAD + col] = b;
          tp[r] = b;
        }
        *reinterpret_cast<u16x4*>(&T[(size_t)col * LDPAD + row0]) = tp;
      } else {
        const float vc = v[col];
#pragma unroll
        for (int r = 0; r < 4; ++r) {
          const float kv = __expf(acc[m][n][r] * INV_EPS);
          const float val = uu[r] * kv * vc;
          Kf[(size_t)(row0 + r) * MP1 + col] = val;
          P[(size_t)(row0 + r) * NCOLS + col] = val;
        }
      }
    }
  }
}

// ---------------------------------------------------------------------------
// Fill dustbin row/col (value exp(z/eps)) in A, T; init v = ones.
// ---------------------------------------------------------------------------
__global__ void edges_kernel(const float* __restrict__ zp,
                             unsigned short* __restrict__ A, unsigned short* __restrict__ T,
                             float* __restrict__ v)
{
  const int i = blockIdx.x * 256 + threadIdx.x;
  if (i >= MP1) return;
  const float E = __expf(zp[0] * INV_EPS);
  const unsigned short eb = f2bf(E);
  A[(size_t)MROWS * LDPAD + i] = eb;
  A[(size_t)i * LDPAD + NCOLS] = eb;
  T[(size_t)NCOLS * LDPAD + i] = eb;
  T[(size_t)i * LDPAD + MROWS] = eb;
  v[i] = 1.0f;
}

// ---------------------------------------------------------------------------
// Final K dustbin row/col: K[i][N] = u_i*E*v_N ; K[M][i] = u_M*E*v_i.
// ---------------------------------------------------------------------------
__global__ void edgeK_kernel(const float* __restrict__ zp, float* __restrict__ Kf,
                             const float* __restrict__ u, const float* __restrict__ v)
{
  const int i = blockIdx.x * 256 + threadIdx.x;
  if (i >= MP1) return;
  const float E = __expf(zp[0] * INV_EPS);
  Kf[(size_t)i * MP1 + NCOLS] = u[i] * E * v[NCOLS];
  Kf[(size_t)MROWS * MP1 + i] = u[MROWS] * E * v[i];
}

// ---------------------------------------------------------------------------
// out[row] = 1 / sum_j Kb[row][j] * x[j]     (rows = cols = 4097)
// one wave per row; 16B bf16 loads (rows 16B-aligned via LDPAD).
// ---------------------------------------------------------------------------
__global__ __launch_bounds__(256) void rowdot_kernel(
    const unsigned short* __restrict__ Kb, const float* __restrict__ x,
    float* __restrict__ out, int rows)
{
  const int lane = threadIdx.x & 63;
  const int wid = threadIdx.x >> 6;
  const int row = blockIdx.x * 4 + wid;
  if (row >= rows) return;
  const unsigned short* rp = Kb + (size_t)row * LDPAD;
  float acc = 0.f;
#pragma unroll
  for (int it = 0; it < 8; ++it) {
    const int j = (it * 64 + lane) * 8;   // 8 bf16 per lane per iter
    const uint4 kv = *reinterpret_cast<const uint4*>(rp + j);
    const float4 x0 = *reinterpret_cast<const float4*>(x + j);
    const float4 x1 = *reinterpret_cast<const float4*>(x + j + 4);
    acc += bf2f(kv.x & 0xffffu) * x0.x;
    acc += bf2f(kv.x >> 16)     * x0.y;
    acc += bf2f(kv.y & 0xffffu) * x0.z;
    acc += bf2f(kv.y >> 16)     * x0.w;
    acc += bf2f(kv.z & 0xffffu) * x1.x;
    acc += bf2f(kv.z >> 16)     * x1.y;
    acc += bf2f(kv.w & 0xffffu) * x1.z;
    acc += bf2f(kv.w >> 16)     * x1.w;
  }
  if (lane == 0) acc += bf2f((unsigned int)rp[4096]) * x[4096];  // tail col 4096
#pragma unroll
  for (int off = 32; off > 0; off >>= 1) acc += __shfl_down(acc, off, 64);
  if (lane == 0) out[row] = 1.0f / acc;
}

extern "C" void kernel_launch(void* const* d_in, const int* in_sizes, int n_in,
                              void* d_out, int out_size, void* d_ws, size_t ws_size,
                              hipStream_t stream) {
  const float* Q = (const float*)d_in[0];
  const float* R = (const float*)d_in[1];
  const float* z = (const float*)d_in[2];

  float* P = (float*)d_out;
  float* Kf = P + (size_t)MROWS * NCOLS;   // K-region of d_out

  const size_t matElems = (size_t)MP1 * LDPAD;   // bf16 elements per matrix
  unsigned short* A = (unsigned short*)d_ws;     // K0 bf16
  unsigned short* T = A + matElems;              // K0^T bf16
  float* u = (float*)(T + matElems);
  float* v = u + UPAD;

  mfma_gemm_kernel<0><<<dim3(32, 32), 256, 0, stream>>>(Q, R, A, T, nullptr, nullptr, nullptr, nullptr);
  edges_kernel<<<(MP1 + 255) / 256, 256, 0, stream>>>(z, A, T, v);
  for (int it = 0; it < 100; ++it) {
    rowdot_kernel<<<(MP1 + 3) / 4, 256, 0, stream>>>(A, v, u, MP1);
    rowdot_kernel<<<(MP1 + 3) / 4, 256, 0, stream>>>(T, u, v, MP1);
  }
  mfma_gemm_kernel<1><<<dim3(32, 32), 256, 0, stream>>>(Q, R, nullptr, nullptr, Kf, P, u, v);
  edgeK_kernel<<<(MP1 + 255) / 256, 256, 0, stream>>>(z, Kf, u, v);
}

// Round 3
// 844.741 us; speedup vs baseline: 1.8710x; 1.7074x over previous
//
#include <hip/hip_runtime.h>
#include <hip/hip_bf16.h>

// Sinkhorn object matching, scaling-vector formulation, fp8 iteration.
//   S = Q R^T (4096x4096, D=256), K0 = exp(S_aug/0.1), dustbin row/col = z
//   100x: u = 1/(K0 v); v = 1/(K0^T u);  K = diag(u) K0 diag(v); P interior.
// A8 = fp8(K0 interior), T8 = fp8(K0^T interior) in d_ws (16.8 MB each).
// Dustbin entries are the constant E = exp(10 z): handled analytically.
// Block b owns rows [16b,16b+16) every dispatch -> XCD b%8 keeps its 2.1 MB
// slice of A8 (and of T8) L2-resident across all 200 matvecs.

#define MROWS 4096
#define NCOLS 4096
#define DDIM 256
#define MP1 4097
#define INV_EPS 10.0f

typedef __attribute__((ext_vector_type(8))) short bf16x8;
typedef __attribute__((ext_vector_type(4))) float f32x4;
typedef __attribute__((ext_vector_type(2))) float f32x2;
typedef __attribute__((ext_vector_type(4))) unsigned short u16x4;

static __device__ __forceinline__ unsigned short f2bf(float f) {
  __hip_bfloat16 h = __float2bfloat16(f);
  union { __hip_bfloat16 h; unsigned short s; } c;
  c.h = h;
  return c.s;
}

// ---------------------------------------------------------------------------
// MFMA bf16 GEMM: 128x128 tile, 4 waves (2x2), wave = 64x64 via 4x4 frags of
// 16x16x32. MODE 0: kv=exp(10S) -> fp8 A8[row][col], fp8 T8[col][row].
// MODE 1: val = u[row]*exp(10S)*v[col] -> fp32 K (stride MP1) and P.
// ---------------------------------------------------------------------------
template <int MODE>
__global__ __launch_bounds__(256) void mfma_gemm_kernel(
    const float* __restrict__ Q, const float* __restrict__ R,
    unsigned char* __restrict__ A8, unsigned char* __restrict__ T8,
    float* __restrict__ Kf, float* __restrict__ P,
    const float* __restrict__ u, const float* __restrict__ v)
{
  __shared__ unsigned short Qs[128][40];
  __shared__ unsigned short Rs[128][40];

  const int tid = threadIdx.x;
  const int lane = tid & 63;
  const int wid = tid >> 6;
  const int wy = wid >> 1;
  const int wx = wid & 1;
  const int rb = blockIdx.y * 128;
  const int cb = blockIdx.x * 128;
  const int lr = tid >> 3;
  const int lf = (tid & 7) * 4;

  f32x4 acc[4][4];
#pragma unroll
  for (int m = 0; m < 4; ++m)
#pragma unroll
    for (int n = 0; n < 4; ++n)
      acc[m][n] = (f32x4){0.f, 0.f, 0.f, 0.f};

  for (int k0 = 0; k0 < DDIM; k0 += 32) {
    float4 qv[4], rv[4];
#pragma unroll
    for (int i = 0; i < 4; ++i) {
      qv[i] = *reinterpret_cast<const float4*>(&Q[(size_t)(rb + lr + 32 * i) * DDIM + k0 + lf]);
      rv[i] = *reinterpret_cast<const float4*>(&R[(size_t)(cb + lr + 32 * i) * DDIM + k0 + lf]);
    }
    __syncthreads();
#pragma unroll
    for (int i = 0; i < 4; ++i) {
      u16x4 qs = {f2bf(qv[i].x), f2bf(qv[i].y), f2bf(qv[i].z), f2bf(qv[i].w)};
      u16x4 rs = {f2bf(rv[i].x), f2bf(rv[i].y), f2bf(rv[i].z), f2bf(rv[i].w)};
      *reinterpret_cast<u16x4*>(&Qs[lr + 32 * i][lf]) = qs;
      *reinterpret_cast<u16x4*>(&Rs[lr + 32 * i][lf]) = rs;
    }
    __syncthreads();

    const int ko = (lane >> 4) * 8;
    const int fr = lane & 15;
    bf16x8 af[4], bg[4];
#pragma unroll
    for (int m = 0; m < 4; ++m)
      af[m] = *reinterpret_cast<const bf16x8*>(&Qs[wy * 64 + m * 16 + fr][ko]);
#pragma unroll
    for (int n = 0; n < 4; ++n)
      bg[n] = *reinterpret_cast<const bf16x8*>(&Rs[wx * 64 + n * 16 + fr][ko]);
#pragma unroll
    for (int m = 0; m < 4; ++m)
#pragma unroll
      for (int n = 0; n < 4; ++n)
        acc[m][n] = __builtin_amdgcn_mfma_f32_16x16x32_bf16(af[m], bg[n], acc[m][n], 0, 0, 0);
  }

  // C/D layout (16x16x32): col = lane&15, row = (lane>>4)*4 + reg.
  const int r0 = (lane >> 4) * 4;
  const int fc = lane & 15;
#pragma unroll
  for (int m = 0; m < 4; ++m) {
    const int row0 = rb + wy * 64 + m * 16 + r0;
    float uu[4];
    if (MODE == 1) {
#pragma unroll
      for (int r = 0; r < 4; ++r) uu[r] = u[row0 + r];
    }
#pragma unroll
    for (int n = 0; n < 4; ++n) {
      const int col = cb + wx * 64 + n * 16 + fc;
      if (MODE == 0) {
        float kv[4];
#pragma unroll
        for (int r = 0; r < 4; ++r) kv[r] = __expf(acc[m][n][r] * INV_EPS);
        int packed = __builtin_amdgcn_cvt_pk_fp8_f32(kv[0], kv[1], 0, false);
        packed = __builtin_amdgcn_cvt_pk_fp8_f32(kv[2], kv[3], packed, true);
        *reinterpret_cast<unsigned int*>(&T8[(size_t)col * NCOLS + row0]) = (unsigned int)packed;
#pragma unroll
        for (int r = 0; r < 4; ++r)
          A8[(size_t)(row0 + r) * NCOLS + col] = (unsigned char)(((unsigned int)packed >> (8 * r)) & 0xffu);
      } else {
        const float vc = v[col];
#pragma unroll
        for (int r = 0; r < 4; ++r) {
          const float kv = __expf(acc[m][n][r] * INV_EPS);
          const float val = uu[r] * kv * vc;
          Kf[(size_t)(row0 + r) * MP1 + col] = val;
          P[(size_t)(row0 + r) * NCOLS + col] = val;
        }
      }
    }
  }
}

// ---------------------------------------------------------------------------
// v = ones (4097)
// ---------------------------------------------------------------------------
__global__ void initv_kernel(float* __restrict__ v)
{
  const int i = blockIdx.x * 1024 + threadIdx.x;
  if (i < MP1) v[i] = 1.0f;
}

// ---------------------------------------------------------------------------
// Final K dustbin row/col.
// ---------------------------------------------------------------------------
__global__ void edgeK_kernel(const float* __restrict__ zp, float* __restrict__ Kf,
                             const float* __restrict__ u, const float* __restrict__ v)
{
  const int i = blockIdx.x * 256 + threadIdx.x;
  if (i >= MP1) return;
  const float E = __expf(zp[0] * INV_EPS);
  Kf[(size_t)i * MP1 + NCOLS] = u[i] * E * v[NCOLS];
  Kf[(size_t)MROWS * MP1 + i] = u[MROWS] * E * v[i];
}

// ---------------------------------------------------------------------------
// out[row] = 1 / (sum_{j<4096} fp8(Kb)[row][j] * x[j] + E * x[4096])
// Blocks 0..255: 16 rows each (wave = row), pinned slice -> XCD b%8 L2.
// Block 256: out[4096] = 1 / (E * sum_{j<=4096} x[j]).
// x staged in LDS as XOR-swizzled 16B chunks (2-way banks).
// ---------------------------------------------------------------------------
__global__ __launch_bounds__(1024) void rowdot8_kernel(
    const unsigned char* __restrict__ Kb, const float* __restrict__ x,
    float* __restrict__ out, const float* __restrict__ zp)
{
  __shared__ float xs[4096 + 32];      // 1024 swizzled float4 chunks + dust
  __shared__ float red[16];

  const int tid = threadIdx.x;
  const int lane = tid & 63;
  const int wid = tid >> 6;
  const float E = __expf(zp[0] * INV_EPS);

  // stage x: thread t -> chunk t stored at swizzled position
  {
    float4 g = *reinterpret_cast<const float4*>(x + tid * 4);
    const int pos = (tid & ~15) | ((tid ^ (tid >> 4)) & 15);
    *reinterpret_cast<float4*>(&xs[pos * 4]) = g;
    if (tid == 0) xs[4096] = x[4096];
  }
  __syncthreads();

  if (blockIdx.x == 256) {
    // dust row: sum all of x
    float s = 0.f;
    {
      const int pos = (tid & ~15) | ((tid ^ (tid >> 4)) & 15);
      float4 g = *reinterpret_cast<const float4*>(&xs[pos * 4]);
      s = g.x + g.y + g.z + g.w;
    }
#pragma unroll
    for (int off = 32; off > 0; off >>= 1) s += __shfl_xor(s, off, 64);
    if (lane == 0) red[wid] = s;
    __syncthreads();
    if (tid == 0) {
      float t = xs[4096];
#pragma unroll
      for (int w = 0; w < 16; ++w) t += red[w];
      out[MROWS] = 1.0f / (E * t);
    }
    return;
  }

  const int row = blockIdx.x * 16 + wid;
  const uint4* rp = reinterpret_cast<const uint4*>(Kb + (size_t)row * NCOLS);
  float acc = 0.f;
#pragma unroll
  for (int qa = 0; qa < 4; ++qa) {
    const uint4 a = rp[lane * 4 + qa];   // cols lane*64 + qa*16 .. +15
    const unsigned int w[4] = {a.x, a.y, a.z, a.w};
#pragma unroll
    for (int t = 0; t < 4; ++t) {
      const int pos = (lane << 4) | (((qa << 2) + t) ^ (lane & 15));
      const float4 xc = *reinterpret_cast<const float4*>(&xs[pos * 4]);
      const f32x2 lo = __builtin_amdgcn_cvt_pk_f32_fp8((int)w[t], false);
      const f32x2 hi = __builtin_amdgcn_cvt_pk_f32_fp8((int)w[t], true);
      acc += lo.x * xc.x + lo.y * xc.y + hi.x * xc.z + hi.y * xc.w;
    }
  }
#pragma unroll
  for (int off = 32; off > 0; off >>= 1) acc += __shfl_xor(acc, off, 64);
  if (lane == 0) out[row] = 1.0f / (acc + E * xs[4096]);
}

extern "C" void kernel_launch(void* const* d_in, const int* in_sizes, int n_in,
                              void* d_out, int out_size, void* d_ws, size_t ws_size,
                              hipStream_t stream) {
  const float* Q = (const float*)d_in[0];
  const float* R = (const float*)d_in[1];
  const float* z = (const float*)d_in[2];

  float* P = (float*)d_out;
  float* Kf = P + (size_t)MROWS * NCOLS;   // K-region of d_out

  unsigned char* A8 = (unsigned char*)d_ws;                   // 16.8 MB
  unsigned char* T8 = A8 + (size_t)MROWS * NCOLS;             // 16.8 MB
  float* u = (float*)(T8 + (size_t)MROWS * NCOLS);
  float* v = u + 4104;

  mfma_gemm_kernel<0><<<dim3(32, 32), 256, 0, stream>>>(Q, R, A8, T8, nullptr, nullptr, nullptr, nullptr);
  initv_kernel<<<5, 1024, 0, stream>>>(v);
  for (int it = 0; it < 100; ++it) {
    rowdot8_kernel<<<257, 1024, 0, stream>>>(A8, v, u, z);
    rowdot8_kernel<<<257, 1024, 0, stream>>>(T8, u, v, z);
  }
  mfma_gemm_kernel<1><<<dim3(32, 32), 256, 0, stream>>>(Q, R, nullptr, nullptr, Kf, P, u, v);
  edgeK_kernel<<<(MP1 + 255) / 256, 256, 0, stream>>>(z, Kf, u, v);
}